// Round 13
// baseline (771.807 us; speedup 1.0000x reference)
//
#include <hip/hip_runtime.h>
#include <stdint.h>
#include <stddef.h>

// ============================================================================
// RegionAttn fused pipeline v13.
//  - NEW ffn_fused: out = LN(relu(FUSED@W1)@W2 + FUSED) in ONE kernel.
//    Per 32-row tile: A in 16KB LDS (verified swizzle), H(32x1024) bf16 in
//    64KB XOR-swizzled LDS (never touches HBM), W1/W2 b-frags from global
//    (1MB, L2-resident), residual re-read from A-LDS. 80KB -> 2 blocks/CU.
//  - Everything else: v12 verbatim (attn19 round-2-exact 60us, XCD-swizzled
//    gemm, gemm_ln, attn4, vectorized scatter).
//
// Workspace (MB): WT@0(2) FE@2(8) Q4@10 K4@18 V4@26 CTX4@34 REF@42(8ea)
//   X2@50(38) Q19@88 K19@126 V19@164 CTX19@202 (38ea) FUSED@88(alias Q19)
// Peak 240 MB (H eliminated).
// ============================================================================

#define DEVINL __device__ __forceinline__

typedef __attribute__((ext_vector_type(8))) short short8;
typedef __attribute__((ext_vector_type(4))) float floatx4;
typedef __attribute__((ext_vector_type(8))) unsigned short ushort8;
typedef __attribute__((ext_vector_type(4))) unsigned short ushort4v;

DEVINL float bf2f(unsigned short u){
  union { unsigned int i; float f; } x; x.i = ((unsigned int)u) << 16; return x.f;
}
DEVINL unsigned short f2bf(float f){
  union { float f; unsigned int i; } x; x.f = f;
  unsigned int r = x.i + 0x7fffu + ((x.i >> 16) & 1u);   // RNE
  return (unsigned short)(r >> 16);
}

typedef __attribute__((address_space(1))) void gvoid_t;
typedef __attribute__((address_space(3))) void lvoid_t;
DEVINL void gload_lds16(const void* g, void* l){
  __builtin_amdgcn_global_load_lds((gvoid_t*)g, (lvoid_t*)l, 16, 0, 0);
}

// ---------------------------------------------------------------------------
// Weight prep: fp32 [K][N] -> bf16 transposed [N][K].
// ---------------------------------------------------------------------------
__global__ __launch_bounds__(256) void wprep_all(
    const float* __restrict__ rq, const float* __restrict__ rk,
    const float* __restrict__ rv, const float* __restrict__ ro,
    const float* __restrict__ lq, const float* __restrict__ lk,
    const float* __restrict__ lv, const float* __restrict__ lo,
    const float* __restrict__ w1, const float* __restrict__ w2,
    unsigned short* __restrict__ wt)
{
  int idx = blockIdx.x * 256 + threadIdx.x;      // 0 .. 1048575
  const float* W; unsigned short* D; int N, r;
  const int K = (idx < 786432) ? 256 : 1024;
  if (idx < 524288){
    int wsel = idx >> 16; r = idx & 65535; N = 256; D = wt + wsel * 65536;
    switch (wsel){
      case 0: W = rq; break; case 1: W = rk; break; case 2: W = rv; break; case 3: W = ro; break;
      case 4: W = lq; break; case 5: W = lk; break; case 6: W = lv; break; default: W = lo; break;
    }
  } else if (idx < 786432){
    r = idx - 524288; N = 1024; D = wt + 524288; W = w1;
  } else {
    r = idx - 786432; N = 256; D = wt + 786432; W = w2;
  }
  int k = r / N, n = r - k * N;
  D[(size_t)n * K + k] = f2bf(W[r]);
}

// ---------------------------------------------------------------------------
// Region avg-pool: x fp32 [B,19,256] -> fe bf16 [B,4,256]
// ---------------------------------------------------------------------------
__global__ __launch_bounds__(256) void pool_kernel(const float* __restrict__ x,
                                                   unsigned short* __restrict__ fe)
{
  const int b = blockIdx.x, d = threadIdx.x;
  const float* xb = x + (size_t)b * 4864 + d;
  float s0 = xb[0*256]+xb[1*256]+xb[5*256]+xb[8*256]+xb[9*256]+xb[10*256]+xb[14*256];
  float s1 = xb[2*256]+xb[11*256]+xb[17*256];
  float s2 = xb[3*256]+xb[12*256]+xb[18*256];
  float s3 = xb[4*256]+xb[6*256]+xb[7*256]+xb[13*256]+xb[15*256]+xb[16*256];
  unsigned short* fb = fe + (size_t)b * 1024 + d;
  fb[0]   = f2bf(s0 * (1.f/7.f));
  fb[256] = f2bf(s1 * (1.f/3.f));
  fb[512] = f2bf(s2 * (1.f/3.f));
  fb[768] = f2bf(s3 * (1.f/6.f));
}

// ---------------------------------------------------------------------------
// GEMM (single-buffer core + XCD-chunked swizzle, v10/v12 verbatim).
// ---------------------------------------------------------------------------
template<int RELU, int SPLIT, int NPAN>
__global__ __launch_bounds__(256, 3)
void gemm_kernel(const unsigned short* __restrict__ A,
                 const unsigned short* __restrict__ Bt,
                 unsigned short* __restrict__ C0,
                 unsigned short* __restrict__ C1,
                 unsigned short* __restrict__ C2,
                 int M, int N, int K)
{
  __shared__ __align__(1024) unsigned short lds[2][8192];  // A 16KB, B 16KB
  const int tid  = threadIdx.x;
  const int wave = tid >> 6, lane = tid & 63;
  const int wm = wave >> 1, wn = wave & 1;

  const int nwg = gridDim.x;
  const int o = blockIdx.x;
  const int g = ((o & 7) * (nwg >> 3)) + (o >> 3);   // XCD-chunked id
  const int rowA0 = (g / NPAN) * 128;
  const int rowB0 = (g % NPAN) * 128;

  const int stg_row = lane >> 3;
  const int stg_kb  = (((lane & 7) ^ (lane >> 3)) << 4);

  floatx4 acc[4][4];
  #pragma unroll
  for (int i = 0; i < 4; ++i)
    #pragma unroll
    for (int j = 0; j < 4; ++j) acc[i][j] = (floatx4){0.f, 0.f, 0.f, 0.f};

  const int nk = K >> 6;
  for (int kt = 0; kt < nk; ++kt){
    if (kt) __syncthreads();
    const int kbase = kt << 7;
    #pragma unroll
    for (int s = 0; s < 4; ++s){
      int chunk = wave * 4 + s;
      int r = chunk * 8 + stg_row;
      gload_lds16((const char*)(A  + (size_t)(rowA0 + r) * K) + kbase + stg_kb,
                  (char*)(&lds[0][0]) + chunk * 1024);
      gload_lds16((const char*)(Bt + (size_t)(rowB0 + r) * K) + kbase + stg_kb,
                  (char*)(&lds[1][0]) + chunk * 1024);
    }
    __syncthreads();
    const char* As = (const char*)(&lds[0][0]);
    const char* Bs = (const char*)(&lds[1][0]);
    #pragma unroll
    for (int kk = 0; kk < 2; ++kk){
      short8 a[4], b[4];
      #pragma unroll
      for (int i = 0; i < 4; ++i){
        int row = wm * 64 + i * 16 + (lane & 15);
        int kb  = (kk * 64 + ((lane >> 4) << 4)) ^ ((row & 7) << 4);
        a[i] = *(const short8*)(As + row * 128 + kb);
      }
      #pragma unroll
      for (int j = 0; j < 4; ++j){
        int row = wn * 64 + j * 16 + (lane & 15);
        int kb  = (kk * 64 + ((lane >> 4) << 4)) ^ ((row & 7) << 4);
        b[j] = *(const short8*)(Bs + row * 128 + kb);
      }
      #pragma unroll
      for (int i = 0; i < 4; ++i)
        #pragma unroll
        for (int j = 0; j < 4; ++j)
          acc[i][j] = __builtin_amdgcn_mfma_f32_16x16x32_bf16(a[i], b[j], acc[i][j], 0, 0, 0);
    }
  }

  unsigned short* dst;
  int colb, ldc;
  if (SPLIT){
    const int seg = rowB0 >> 8;
    dst = (seg == 0) ? C0 : (seg == 1) ? C1 : C2;
    colb = rowB0 & 255;
    ldc = 256;
  } else {
    dst = C0; colb = rowB0; ldc = N;
  }
  const int cr = (lane >> 4) << 2;
  const int cc = lane & 15;
  #pragma unroll
  for (int i = 0; i < 4; ++i){
    #pragma unroll
    for (int j = 0; j < 4; ++j){
      int r0 = rowA0 + wm * 64 + i * 16 + cr;
      int c0 = colb + wn * 64 + j * 16 + cc;
      #pragma unroll
      for (int r = 0; r < 4; ++r){
        float v = acc[i][j][r];
        if (RELU) v = fmaxf(v, 0.f);
        dst[(size_t)(r0 + r) * ldc + c0] = f2bf(v);
      }
    }
  }
}

// ---------------------------------------------------------------------------
// gemm_ln v2: Out[M,256] = LN(A[M,K] @ Bt[256,K]^T + Res[M,256]).
// (verified; used for the two attention out-projections)
// ---------------------------------------------------------------------------
template<int OUTF32>
__global__ __launch_bounds__(512, 4)
void gemm_ln_kernel(const unsigned short* __restrict__ A,
                    const unsigned short* __restrict__ Bt,
                    const unsigned short* __restrict__ Res,
                    void* __restrict__ Out, int M, int K)
{
  __shared__ __align__(1024) char lds[2][40960];   // A@0 (8KB), B@8192 (32KB)
  const int tid  = threadIdx.x;
  const int wave = tid >> 6, lane = tid & 63;
  const int wm = wave >> 2, wn = wave & 3;
  const int rowA0 = blockIdx.x * 64;
  const int stg_row = lane >> 3;
  const int stg_kb  = (((lane & 7) ^ (lane >> 3)) << 4);

  floatx4 acc[2][4];
  #pragma unroll
  for (int i = 0; i < 2; ++i)
    #pragma unroll
    for (int j = 0; j < 4; ++j) acc[i][j] = (floatx4){0.f, 0.f, 0.f, 0.f};

  const int nk = K >> 6;
  int cur = 0;
  #pragma unroll
  for (int s = 0; s < 5; ++s){
    int chunk = wave * 5 + s;
    const unsigned short* src = (chunk < 8)
      ? A  + (size_t)(rowA0 + chunk * 8 + stg_row) * K
      : Bt + (size_t)((chunk - 8) * 8 + stg_row) * K;
    gload_lds16((const char*)src + stg_kb, &lds[0][0] + chunk * 1024);
  }
  __syncthreads();

  for (int kt = 0; kt < nk; ++kt){
    if (kt + 1 < nk){
      const int kbase = (kt + 1) << 7;
      #pragma unroll
      for (int s = 0; s < 5; ++s){
        int chunk = wave * 5 + s;
        const unsigned short* src = (chunk < 8)
          ? A  + (size_t)(rowA0 + chunk * 8 + stg_row) * K
          : Bt + (size_t)((chunk - 8) * 8 + stg_row) * K;
        gload_lds16((const char*)src + kbase + stg_kb, &lds[cur ^ 1][0] + chunk * 1024);
      }
    }
    const char* As = &lds[cur][0];
    const char* Bs = &lds[cur][0] + 8192;
    #pragma unroll
    for (int kk = 0; kk < 2; ++kk){
      short8 a[2], b[4];
      #pragma unroll
      for (int i = 0; i < 2; ++i){
        int row = wm * 32 + i * 16 + (lane & 15);
        int kb  = (kk * 64 + ((lane >> 4) << 4)) ^ ((row & 7) << 4);
        a[i] = *(const short8*)(As + row * 128 + kb);
      }
      #pragma unroll
      for (int j = 0; j < 4; ++j){
        int row = wn * 64 + j * 16 + (lane & 15);
        int kb  = (kk * 64 + ((lane >> 4) << 4)) ^ ((row & 7) << 4);
        b[j] = *(const short8*)(Bs + row * 128 + kb);
      }
      #pragma unroll
      for (int i = 0; i < 2; ++i)
        #pragma unroll
        for (int j = 0; j < 4; ++j)
          acc[i][j] = __builtin_amdgcn_mfma_f32_16x16x32_bf16(a[i], b[j], acc[i][j], 0, 0, 0);
    }
    __syncthreads();
    cur ^= 1;
  }

  float* red_s = (float*)&lds[0][0];     // [4][64]
  float* red_q = red_s + 256;            // [4][64]
  float* mu_a  = red_s + 512;            // [64]
  float* rs_a  = red_s + 576;            // [64]
  const int g  = lane >> 4;
  const int cl = lane & 15;
  #pragma unroll
  for (int i = 0; i < 2; ++i){
    #pragma unroll
    for (int r = 0; r < 4; ++r){
      const int rowl = wm * 32 + i * 16 + g * 4 + r;
      float s = 0.f, q = 0.f;
      #pragma unroll
      for (int j = 0; j < 4; ++j){
        float v = acc[i][j][r] +
                  bf2f(Res[(size_t)(rowA0 + rowl) * 256 + wn * 64 + j * 16 + cl]);
        acc[i][j][r] = v;
        s += v; q += v * v;
      }
      #pragma unroll
      for (int off = 1; off < 16; off <<= 1){
        s += __shfl_xor(s, off); q += __shfl_xor(q, off);
      }
      if (cl == 0){ red_s[wn * 64 + rowl] = s; red_q[wn * 64 + rowl] = q; }
    }
  }
  __syncthreads();
  if (tid < 64){
    float S = red_s[tid] + red_s[64 + tid] + red_s[128 + tid] + red_s[192 + tid];
    float Q = red_q[tid] + red_q[64 + tid] + red_q[128 + tid] + red_q[192 + tid];
    float mu = S * (1.f / 256.f);
    float var = Q * (1.f / 256.f) - mu * mu;
    mu_a[tid] = mu;
    rs_a[tid] = rsqrtf(var + 1e-5f);
  }
  __syncthreads();
  #pragma unroll
  for (int i = 0; i < 2; ++i){
    #pragma unroll
    for (int r = 0; r < 4; ++r){
      const int rowl = wm * 32 + i * 16 + g * 4 + r;
      const float mu = mu_a[rowl], rs = rs_a[rowl];
      #pragma unroll
      for (int j = 0; j < 4; ++j){
        float w = (acc[i][j][r] - mu) * rs;
        size_t idx = (size_t)(rowA0 + rowl) * 256 + wn * 64 + j * 16 + cl;
        if (OUTF32) ((float*)Out)[idx] = w;
        else        ((unsigned short*)Out)[idx] = f2bf(w);
      }
    }
  }
}

// ---------------------------------------------------------------------------
// ffn_fused: Out[M,256] = LN(relu(A@W1t^T)@W2t^T + A), fp32 out.
// 32 rows/block, 512 thr (8 waves 2x4). A in 16KB swizzled LDS; H(32x1024)
// bf16 in 64KB LDS, swizzle byte = row*2048 + ((k*2)^((row&7)<<4)).
// W1t[1024][256], W2t[256][1024] b-frags straight from global (L2-hot).
// All MFMA operand pairs share k-map kk*32+(lane>>4)*8+e (verified bijection).
// ---------------------------------------------------------------------------
__global__ __launch_bounds__(512, 4)
void ffn_fused_kernel(const unsigned short* __restrict__ A,
                      const unsigned short* __restrict__ W1t,
                      const unsigned short* __restrict__ W2t,
                      float* __restrict__ Out, int M)
{
  __shared__ __align__(1024) unsigned short Al[8192];    // 16KB: panel p@p*4096
  __shared__ __align__(1024) unsigned short Hl[32768];   // 64KB: [32][1024] swz
  const int tid  = threadIdx.x;
  const int wave = tid >> 6, lane = tid & 63;
  const int wm = wave >> 2, wn = wave & 3;   // 2 x 4
  const int rowA0 = blockIdx.x * 32;
  const int ko = (lane >> 4) << 3;           // k elem offset within 32-slice

  // stage A: 16 chunks of 1KB; chunk c = p*4+rg -> rows rg*8.., panel p
  const int stg_row = lane >> 3;
  const int stg_kb  = (((lane & 7) ^ (lane >> 3)) << 4);
  #pragma unroll
  for (int s = 0; s < 2; ++s){
    int c = wave * 2 + s;
    int p = c >> 2, rg = c & 3;
    int r = rg * 8 + stg_row;
    gload_lds16((const char*)(A + (size_t)(rowA0 + r) * 256 + p * 64) + stg_kb,
                (char*)Al + c * 1024);
  }
  __syncthreads();

  // hoist the 8 A-fragments (reused for all 16 H-panels)
  short8 af[8];
  {
    const int row = wm * 16 + (lane & 15);
    const int rx = (row & 7) << 4;
    #pragma unroll
    for (int kk = 0; kk < 8; ++kk){
      int kb = (((kk & 1) << 6) + ((lane >> 4) << 4)) ^ rx;
      af[kk] = *(const short8*)((const char*)Al + (kk >> 1) * 4096 + row * 128 + kb);
    }
  }

  // phase 1: H = relu(A @ W1t^T), 16 panels of 64 cols
  const int w1r = wn * 16 + (lane & 15);
  for (int p = 0; p < 16; ++p){
    floatx4 acc = (floatx4){0.f, 0.f, 0.f, 0.f};
    #pragma unroll
    for (int kk = 0; kk < 8; ++kk){
      short8 b = *(const short8*)(W1t + (size_t)(p * 64 + w1r) * 256 + kk * 32 + ko);
      acc = __builtin_amdgcn_mfma_f32_16x16x32_bf16(af[kk], b, acc, 0, 0, 0);
    }
    const int hcol = p * 64 + wn * 16 + (lane & 15);
    #pragma unroll
    for (int r = 0; r < 4; ++r){
      const int arow = wm * 16 + ((lane >> 4) << 2) + r;
      *(unsigned short*)((char*)Hl + arow * 2048 + ((hcol * 2) ^ ((arow & 7) << 4)))
          = f2bf(fmaxf(acc[r], 0.f));
    }
  }
  __syncthreads();

  // phase 2: C = H @ W2t^T (K=1024), wave tile 16x64
  floatx4 acc2[4];
  #pragma unroll
  for (int j = 0; j < 4; ++j) acc2[j] = (floatx4){0.f, 0.f, 0.f, 0.f};
  {
    const int row = wm * 16 + (lane & 15);
    const int rx = (row & 7) << 4;
    for (int kk = 0; kk < 32; ++kk){
      short8 a = *(const short8*)((const char*)Hl + row * 2048 +
                                  ((kk * 64 + ((lane >> 4) << 4)) ^ rx));
      #pragma unroll
      for (int j = 0; j < 4; ++j){
        short8 b = *(const short8*)(W2t + (size_t)(wn * 64 + j * 16 + (lane & 15)) * 1024
                                    + kk * 32 + ko);
        acc2[j] = __builtin_amdgcn_mfma_f32_16x16x32_bf16(a, b, acc2[j], 0, 0, 0);
      }
    }
  }
  __syncthreads();   // all H reads done -> Hl reusable for LN reductions

  // epilogue: residual (from A-LDS) + per-row LN over 256 cols
  float* red_s = (float*)Hl;           // [4][32]
  float* red_q = red_s + 128;          // [4][32]
  float* mu_a  = red_s + 256;          // [32]
  float* rs_a  = red_s + 288;          // [32]
  const int g  = lane >> 4;
  const int cl = lane & 15;
  #pragma unroll
  for (int r = 0; r < 4; ++r){
    const int rowl = wm * 16 + g * 4 + r;
    float s = 0.f, q = 0.f;
    #pragma unroll
    for (int j = 0; j < 4; ++j){
      const int col = wn * 64 + j * 16 + cl;
      unsigned short resb = *(const unsigned short*)((const char*)Al + (col >> 6) * 4096
                              + rowl * 128 + (((col & 63) * 2) ^ ((rowl & 7) << 4)));
      float v = acc2[j][r] + bf2f(resb);
      acc2[j][r] = v;
      s += v; q += v * v;
    }
    #pragma unroll
    for (int off = 1; off < 16; off <<= 1){
      s += __shfl_xor(s, off); q += __shfl_xor(q, off);
    }
    if (cl == 0){ red_s[wn * 32 + rowl] = s; red_q[wn * 32 + rowl] = q; }
  }
  __syncthreads();
  if (tid < 32){
    float S = red_s[tid] + red_s[32 + tid] + red_s[64 + tid] + red_s[96 + tid];
    float Q = red_q[tid] + red_q[32 + tid] + red_q[64 + tid] + red_q[96 + tid];
    float mu = S * (1.f / 256.f);
    float var = Q * (1.f / 256.f) - mu * mu;
    mu_a[tid] = mu;
    rs_a[tid] = rsqrtf(var + 1e-5f);
  }
  __syncthreads();
  #pragma unroll
  for (int r = 0; r < 4; ++r){
    const int rowl = wm * 16 + g * 4 + r;
    const float mu = mu_a[rowl], rs = rs_a[rowl];
    #pragma unroll
    for (int j = 0; j < 4; ++j){
      Out[(size_t)(rowA0 + rowl) * 256 + wn * 64 + j * 16 + cl] = (acc2[j][r] - mu) * rs;
    }
  }
}

// ---------------------------------------------------------------------------
// rsa attention (round-2 verbatim): 4 tokens, 8 heads; separate Q/K/V.
// ---------------------------------------------------------------------------
__global__ __launch_bounds__(256) void attn4_kernel(
    const unsigned short* __restrict__ Q, const unsigned short* __restrict__ K,
    const unsigned short* __restrict__ V, unsigned short* __restrict__ ctx)
{
  const int t = threadIdx.x;
  const int lb = t >> 5, u = t & 31, h = u >> 2, q = u & 3;
  const size_t b = (size_t)blockIdx.x * 8 + lb;
  const size_t base = b * 1024 + h * 32;

  float qf[32];
  {
    const ushort8* qp = (const ushort8*)(Q + base + q * 256);
    #pragma unroll
    for (int g = 0; g < 4; ++g){
      ushort8 v = qp[g];
      #pragma unroll
      for (int e = 0; e < 8; ++e) qf[g * 8 + e] = bf2f(v[e]);
    }
  }
  float sc[4];
  #pragma unroll
  for (int s = 0; s < 4; ++s){
    const ushort8* kp = (const ushort8*)(K + base + s * 256);
    float a0 = 0, a1 = 0, a2 = 0, a3 = 0;
    #pragma unroll
    for (int g = 0; g < 4; ++g){
      ushort8 v = kp[g];
      a0 += qf[g*8+0]*bf2f(v[0]); a1 += qf[g*8+1]*bf2f(v[1]);
      a2 += qf[g*8+2]*bf2f(v[2]); a3 += qf[g*8+3]*bf2f(v[3]);
      a0 += qf[g*8+4]*bf2f(v[4]); a1 += qf[g*8+5]*bf2f(v[5]);
      a2 += qf[g*8+6]*bf2f(v[6]); a3 += qf[g*8+7]*bf2f(v[7]);
    }
    sc[s] = ((a0 + a1) + (a2 + a3)) * 0.17677669529663687f;
  }
  float m = fmaxf(fmaxf(sc[0], sc[1]), fmaxf(sc[2], sc[3]));
  float sum = 0.f;
  #pragma unroll
  for (int s = 0; s < 4; ++s){ sc[s] = __expf(sc[s] - m); sum += sc[s]; }
  float inv = 1.f / sum;

  float o[32];
  #pragma unroll
  for (int d = 0; d < 32; ++d) o[d] = 0.f;
  #pragma unroll
  for (int s = 0; s < 4; ++s){
    float p = sc[s] * inv;
    const ushort8* vp = (const ushort8*)(V + base + s * 256);
    #pragma unroll
    for (int g = 0; g < 4; ++g){
      ushort8 v = vp[g];
      #pragma unroll
      for (int e = 0; e < 8; ++e) o[g * 8 + e] += p * bf2f(v[e]);
    }
  }
  unsigned short* cp = ctx + base + q * 256;
  #pragma unroll
  for (int g = 0; g < 4; ++g){
    ushort8 w;
    #pragma unroll
    for (int e = 0; e < 8; ++e) w[e] = f2bf(o[g * 8 + e]);
    ((ushort8*)cp)[g] = w;
  }
}

// ---------------------------------------------------------------------------
// scatter v2 (vectorized): x2[b,c,d] = x[b,c,d] + ref[b, rid[c], d].
// ---------------------------------------------------------------------------
__global__ __launch_bounds__(256) void scatter_kernel(
    const float* __restrict__ x, const unsigned short* __restrict__ ref,
    unsigned short* __restrict__ x2)
{
  const int b = blockIdx.x, t = threadIdx.x;
  const int d0 = (t & 63) * 4;
  const int cbase = t >> 6;                    // 0..3, wave-uniform
  float rv[4][4];
  #pragma unroll
  for (int r = 0; r < 4; ++r){
    ushort4v rr = *(const ushort4v*)(ref + (size_t)b * 1024 + r * 256 + d0);
    #pragma unroll
    for (int e = 0; e < 4; ++e) rv[r][e] = bf2f(rr[e]);
  }
  const unsigned long long packed = 0x27CE40F390ull;  // rid[c] at bits [2c+1:2c]
  #pragma unroll
  for (int k = 0; k < 5; ++k){
    int c = cbase + k * 4;
    if (c < 19){
      int r = (int)((packed >> (2 * c)) & 3ull);
      floatx4 xv = *(const floatx4*)(x + (size_t)b * 4864 + c * 256 + d0);
      ushort4v w;
      #pragma unroll
      for (int e = 0; e < 4; ++e) w[e] = f2bf(xv[e] + rv[r][e]);
      *(ushort4v*)(x2 + (size_t)b * 4864 + c * 256 + d0) = w;
    }
  }
}

// ---------------------------------------------------------------------------
// lsa attention (round-2 EXACT, best measured 60.2us).
// ---------------------------------------------------------------------------
__global__ __launch_bounds__(256) void attn19_kernel(
    const unsigned short* __restrict__ Q, const unsigned short* __restrict__ K,
    const unsigned short* __restrict__ V, unsigned short* __restrict__ ctx)
{
  __shared__ float Kl[4864];
  __shared__ float Vl[4864];
  const size_t b = blockIdx.x;
  const unsigned short* Kb = K + b * 4864;
  const unsigned short* Vb = V + b * 4864;
  for (int i = threadIdx.x; i < 4864; i += 256){ Kl[i] = bf2f(Kb[i]); Vl[i] = bf2f(Vb[i]); }
  __syncthreads();
  const int t = threadIdx.x;
  if (t >= 152) return;
  const int h = t / 19, qq = t - h * 19;

  float qf[32];
  {
    const ushort8* qp = (const ushort8*)(Q + b * 4864 + qq * 256 + h * 32);
    #pragma unroll
    for (int g = 0; g < 4; ++g){
      ushort8 v = qp[g];
      #pragma unroll
      for (int e = 0; e < 8; ++e) qf[g * 8 + e] = bf2f(v[e]);
    }
  }
  float p[19];
  float m = -1e30f;
  #pragma unroll
  for (int s = 0; s < 19; ++s){
    const float* kr = &Kl[s * 256 + h * 32];
    float a0 = 0, a1 = 0, a2 = 0, a3 = 0;
    #pragma unroll
    for (int d = 0; d < 32; d += 4){
      a0 += qf[d+0] * kr[d+0]; a1 += qf[d+1] * kr[d+1];
      a2 += qf[d+2] * kr[d+2]; a3 += qf[d+3] * kr[d+3];
    }
    p[s] = ((a0 + a1) + (a2 + a3)) * 0.17677669529663687f;
    m = fmaxf(m, p[s]);
  }
  float sum = 0.f;
  #pragma unroll
  for (int s = 0; s < 19; ++s){ p[s] = __expf(p[s] - m); sum += p[s]; }
  float inv = 1.f / sum;

  float o[32];
  #pragma unroll
  for (int d = 0; d < 32; ++d) o[d] = 0.f;
  #pragma unroll
  for (int s = 0; s < 19; ++s){
    float ps = p[s] * inv;
    const float* vr = &Vl[s * 256 + h * 32];
    #pragma unroll
    for (int d = 0; d < 32; ++d) o[d] += ps * vr[d];
  }
  unsigned short* cp = ctx + b * 4864 + qq * 256 + h * 32;
  #pragma unroll
  for (int g = 0; g < 4; ++g){
    ushort8 w;
    #pragma unroll
    for (int e = 0; e < 8; ++e) w[e] = f2bf(o[g * 8 + e]);
    ((ushort8*)cp)[g] = w;
  }
}

// ============================================================================
extern "C" void kernel_launch(void* const* d_in, const int* in_sizes, int n_in,
                              void* d_out, int out_size, void* d_ws, size_t ws_size,
                              hipStream_t stream)
{
  (void)n_in; (void)out_size;
  const float* x  = (const float*)d_in[0];
  const float* rq = (const float*)d_in[1];
  const float* rk = (const float*)d_in[2];
  const float* rv = (const float*)d_in[3];
  const float* ro = (const float*)d_in[4];
  const float* lq = (const float*)d_in[5];
  const float* lk = (const float*)d_in[6];
  const float* lv = (const float*)d_in[7];
  const float* lo = (const float*)d_in[8];
  const float* w1 = (const float*)d_in[9];
  const float* w2 = (const float*)d_in[10];

  const int B = in_sizes[0] / 4864;          // 4096
  const int M4  = B * 4;                     // 16384
  const int M19 = B * 19;                    // 77824
  const size_t MB = 1ull << 20;
  if (ws_size < 240 * MB) return;

  char* ws = (char*)d_ws;
  unsigned short* WT    = (unsigned short*)(ws);
  unsigned short* FE    = (unsigned short*)(ws + 2   * MB);
  unsigned short* Q4    = (unsigned short*)(ws + 10  * MB);
  unsigned short* K4    = (unsigned short*)(ws + 18  * MB);
  unsigned short* V4    = (unsigned short*)(ws + 26  * MB);
  unsigned short* CTX4  = (unsigned short*)(ws + 34  * MB);
  unsigned short* REF   = (unsigned short*)(ws + 42  * MB);
  unsigned short* X2    = (unsigned short*)(ws + 50  * MB);
  unsigned short* Q19   = (unsigned short*)(ws + 88  * MB);
  unsigned short* K19   = (unsigned short*)(ws + 126 * MB);
  unsigned short* V19   = (unsigned short*)(ws + 164 * MB);
  unsigned short* CTX19 = (unsigned short*)(ws + 202 * MB);
  unsigned short* FUSED = (unsigned short*)(ws + 88  * MB);  // alias Q19 (dead)
  float* out = (float*)d_out;

  // 1. weights -> bf16 [n][k]
  wprep_all<<<4096, 256, 0, stream>>>(rq, rk, rv, ro, lq, lk, lv, lo, w1, w2, WT);
  // 2. region pool
  pool_kernel<<<B, 256, 0, stream>>>(x, FE);
  // 3. rsa QKV (one pass, split epilogue)
  gemm_kernel<0,1,6><<<6 * (M4/128), 256, 0, stream>>>(FE, WT, Q4, K4, V4, M4, 768, 256);
  // 4. rsa attention
  attn4_kernel<<<B/8, 256, 0, stream>>>(Q4, K4, V4, CTX4);
  // 5. rsa out-proj + LN(.. + fe) -> REF
  gemm_ln_kernel<0><<<M4/64, 512, 0, stream>>>(CTX4, WT + 3*65536, FE, REF, M4, 256);
  // 6. x2 = x + ref[rid]
  scatter_kernel<<<B, 256, 0, stream>>>(x, REF, X2);
  // 7. lsa QKV (one pass, split epilogue)
  gemm_kernel<0,1,6><<<6 * (M19/128), 256, 0, stream>>>(X2, WT + 4*65536, Q19, K19, V19, M19, 768, 256);
  // 8. lsa attention
  attn19_kernel<<<B, 256, 0, stream>>>(Q19, K19, V19, CTX19);
  // 9. lsa out-proj + LN(.. + x2) -> FUSED   (Q19 dead)
  gemm_ln_kernel<0><<<M19/64, 512, 0, stream>>>(CTX19, WT + 7*65536, X2, FUSED, M19, 256);
  // 10. fused FFN: out = LN(relu(FUSED@w1)@w2 + FUSED)  (no H buffer)
  ffn_fused_kernel<<<M19/32, 512, 0, stream>>>(FUSED, WT + 524288, WT + 786432, out, M19);
}

// Round 14
// 366.573 us; speedup vs baseline: 2.1055x; 2.1055x over previous
//
#include <hip/hip_runtime.h>
#include <stdint.h>
#include <stddef.h>

// ============================================================================
// RegionAttn fused pipeline v14 == v12 (revert of failed ffn_fused).
//  - attn19: round-2 EXACT (best measured 60.2us).
//  - scatter: vectorized (float4 x-reads, ushort4 stores, bit-packed rid).
//  - gemm: single-buffer core + XCD-chunked swizzle; SPLIT epilogue for QKV.
//  - gemm_ln: out-projections + FFN w2 (+LN fused).
//
// Workspace map (MB offsets, sizes exact):
//   WT  @0(2)  FE @2(8)  Q4 @10(8)  K4 @18(8)  V4 @26(8)  CTX4 @34(8)
//   REF @42(8) X2 @50(38) Q19 @88(38) K19 @126(38) V19 @164(38) CTX19 @202(38)
//   FUSED @88 (alias Q19, dead)   H @126 (76MB, alias K19+V19, dead)
// Peak 240 MB.
// ============================================================================

#define DEVINL __device__ __forceinline__

typedef __attribute__((ext_vector_type(8))) short short8;
typedef __attribute__((ext_vector_type(4))) float floatx4;
typedef __attribute__((ext_vector_type(8))) unsigned short ushort8;
typedef __attribute__((ext_vector_type(4))) unsigned short ushort4v;

DEVINL float bf2f(unsigned short u){
  union { unsigned int i; float f; } x; x.i = ((unsigned int)u) << 16; return x.f;
}
DEVINL unsigned short f2bf(float f){
  union { float f; unsigned int i; } x; x.f = f;
  unsigned int r = x.i + 0x7fffu + ((x.i >> 16) & 1u);   // RNE
  return (unsigned short)(r >> 16);
}

typedef __attribute__((address_space(1))) void gvoid_t;
typedef __attribute__((address_space(3))) void lvoid_t;
DEVINL void gload_lds16(const void* g, void* l){
  __builtin_amdgcn_global_load_lds((gvoid_t*)g, (lvoid_t*)l, 16, 0, 0);
}

// ---------------------------------------------------------------------------
// Weight prep: fp32 [K][N] -> bf16 transposed [N][K].
// ---------------------------------------------------------------------------
__global__ __launch_bounds__(256) void wprep_all(
    const float* __restrict__ rq, const float* __restrict__ rk,
    const float* __restrict__ rv, const float* __restrict__ ro,
    const float* __restrict__ lq, const float* __restrict__ lk,
    const float* __restrict__ lv, const float* __restrict__ lo,
    const float* __restrict__ w1, const float* __restrict__ w2,
    unsigned short* __restrict__ wt)
{
  int idx = blockIdx.x * 256 + threadIdx.x;      // 0 .. 1048575
  const float* W; unsigned short* D; int N, r;
  const int K = (idx < 786432) ? 256 : 1024;
  if (idx < 524288){
    int wsel = idx >> 16; r = idx & 65535; N = 256; D = wt + wsel * 65536;
    switch (wsel){
      case 0: W = rq; break; case 1: W = rk; break; case 2: W = rv; break; case 3: W = ro; break;
      case 4: W = lq; break; case 5: W = lk; break; case 6: W = lv; break; default: W = lo; break;
    }
  } else if (idx < 786432){
    r = idx - 524288; N = 1024; D = wt + 524288; W = w1;
  } else {
    r = idx - 786432; N = 256; D = wt + 786432; W = w2;
  }
  int k = r / N, n = r - k * N;
  D[(size_t)n * K + k] = f2bf(W[r]);
}

// ---------------------------------------------------------------------------
// Region avg-pool: x fp32 [B,19,256] -> fe bf16 [B,4,256]
// ---------------------------------------------------------------------------
__global__ __launch_bounds__(256) void pool_kernel(const float* __restrict__ x,
                                                   unsigned short* __restrict__ fe)
{
  const int b = blockIdx.x, d = threadIdx.x;
  const float* xb = x + (size_t)b * 4864 + d;
  float s0 = xb[0*256]+xb[1*256]+xb[5*256]+xb[8*256]+xb[9*256]+xb[10*256]+xb[14*256];
  float s1 = xb[2*256]+xb[11*256]+xb[17*256];
  float s2 = xb[3*256]+xb[12*256]+xb[18*256];
  float s3 = xb[4*256]+xb[6*256]+xb[7*256]+xb[13*256]+xb[15*256]+xb[16*256];
  unsigned short* fb = fe + (size_t)b * 1024 + d;
  fb[0]   = f2bf(s0 * (1.f/7.f));
  fb[256] = f2bf(s1 * (1.f/3.f));
  fb[512] = f2bf(s2 * (1.f/3.f));
  fb[768] = f2bf(s3 * (1.f/6.f));
}

// ---------------------------------------------------------------------------
// GEMM (single-buffer core + XCD-chunked swizzle).
// 1-D grid of NPAN*mtiles blocks (%8==0). g = (o&7)*(nwg/8)+(o>>3);
// panel = g%NPAN (fastest) -> same-A-tile blocks share one XCD's L2.
// SPLIT=1: N==768, output to C0|C1|C2 [M,256] by 256-segment.
// ---------------------------------------------------------------------------
template<int RELU, int SPLIT, int NPAN>
__global__ __launch_bounds__(256, 3)
void gemm_kernel(const unsigned short* __restrict__ A,
                 const unsigned short* __restrict__ Bt,
                 unsigned short* __restrict__ C0,
                 unsigned short* __restrict__ C1,
                 unsigned short* __restrict__ C2,
                 int M, int N, int K)
{
  __shared__ __align__(1024) unsigned short lds[2][8192];  // A 16KB, B 16KB
  const int tid  = threadIdx.x;
  const int wave = tid >> 6, lane = tid & 63;
  const int wm = wave >> 1, wn = wave & 1;

  const int nwg = gridDim.x;
  const int o = blockIdx.x;
  const int g = ((o & 7) * (nwg >> 3)) + (o >> 3);   // XCD-chunked id
  const int rowA0 = (g / NPAN) * 128;
  const int rowB0 = (g % NPAN) * 128;

  const int stg_row = lane >> 3;
  const int stg_kb  = (((lane & 7) ^ (lane >> 3)) << 4);

  floatx4 acc[4][4];
  #pragma unroll
  for (int i = 0; i < 4; ++i)
    #pragma unroll
    for (int j = 0; j < 4; ++j) acc[i][j] = (floatx4){0.f, 0.f, 0.f, 0.f};

  const int nk = K >> 6;
  for (int kt = 0; kt < nk; ++kt){
    if (kt) __syncthreads();
    const int kbase = kt << 7;
    #pragma unroll
    for (int s = 0; s < 4; ++s){
      int chunk = wave * 4 + s;
      int r = chunk * 8 + stg_row;
      gload_lds16((const char*)(A  + (size_t)(rowA0 + r) * K) + kbase + stg_kb,
                  (char*)(&lds[0][0]) + chunk * 1024);
      gload_lds16((const char*)(Bt + (size_t)(rowB0 + r) * K) + kbase + stg_kb,
                  (char*)(&lds[1][0]) + chunk * 1024);
    }
    __syncthreads();
    const char* As = (const char*)(&lds[0][0]);
    const char* Bs = (const char*)(&lds[1][0]);
    #pragma unroll
    for (int kk = 0; kk < 2; ++kk){
      short8 a[4], b[4];
      #pragma unroll
      for (int i = 0; i < 4; ++i){
        int row = wm * 64 + i * 16 + (lane & 15);
        int kb  = (kk * 64 + ((lane >> 4) << 4)) ^ ((row & 7) << 4);
        a[i] = *(const short8*)(As + row * 128 + kb);
      }
      #pragma unroll
      for (int j = 0; j < 4; ++j){
        int row = wn * 64 + j * 16 + (lane & 15);
        int kb  = (kk * 64 + ((lane >> 4) << 4)) ^ ((row & 7) << 4);
        b[j] = *(const short8*)(Bs + row * 128 + kb);
      }
      #pragma unroll
      for (int i = 0; i < 4; ++i)
        #pragma unroll
        for (int j = 0; j < 4; ++j)
          acc[i][j] = __builtin_amdgcn_mfma_f32_16x16x32_bf16(a[i], b[j], acc[i][j], 0, 0, 0);
    }
  }

  unsigned short* dst;
  int colb, ldc;
  if (SPLIT){
    const int seg = rowB0 >> 8;
    dst = (seg == 0) ? C0 : (seg == 1) ? C1 : C2;
    colb = rowB0 & 255;
    ldc = 256;
  } else {
    dst = C0; colb = rowB0; ldc = N;
  }
  const int cr = (lane >> 4) << 2;
  const int cc = lane & 15;
  #pragma unroll
  for (int i = 0; i < 4; ++i){
    #pragma unroll
    for (int j = 0; j < 4; ++j){
      int r0 = rowA0 + wm * 64 + i * 16 + cr;
      int c0 = colb + wn * 64 + j * 16 + cc;
      #pragma unroll
      for (int r = 0; r < 4; ++r){
        float v = acc[i][j][r];
        if (RELU) v = fmaxf(v, 0.f);
        dst[(size_t)(r0 + r) * ldc + c0] = f2bf(v);
      }
    }
  }
}

// ---------------------------------------------------------------------------
// gemm_ln v2: Out[M,256] = LN(A[M,K] @ Bt[256,K]^T + Res[M,256]).
// BM=64, BN=256, BK=64, 512 thr (8 waves 2x4). (verified)
// ---------------------------------------------------------------------------
template<int OUTF32>
__global__ __launch_bounds__(512, 4)
void gemm_ln_kernel(const unsigned short* __restrict__ A,
                    const unsigned short* __restrict__ Bt,
                    const unsigned short* __restrict__ Res,
                    void* __restrict__ Out, int M, int K)
{
  __shared__ __align__(1024) char lds[2][40960];   // A@0 (8KB), B@8192 (32KB)
  const int tid  = threadIdx.x;
  const int wave = tid >> 6, lane = tid & 63;
  const int wm = wave >> 2, wn = wave & 3;
  const int rowA0 = blockIdx.x * 64;
  const int stg_row = lane >> 3;
  const int stg_kb  = (((lane & 7) ^ (lane >> 3)) << 4);

  floatx4 acc[2][4];
  #pragma unroll
  for (int i = 0; i < 2; ++i)
    #pragma unroll
    for (int j = 0; j < 4; ++j) acc[i][j] = (floatx4){0.f, 0.f, 0.f, 0.f};

  const int nk = K >> 6;
  int cur = 0;
  #pragma unroll
  for (int s = 0; s < 5; ++s){
    int chunk = wave * 5 + s;
    const unsigned short* src = (chunk < 8)
      ? A  + (size_t)(rowA0 + chunk * 8 + stg_row) * K
      : Bt + (size_t)((chunk - 8) * 8 + stg_row) * K;
    gload_lds16((const char*)src + stg_kb, &lds[0][0] + chunk * 1024);
  }
  __syncthreads();

  for (int kt = 0; kt < nk; ++kt){
    if (kt + 1 < nk){
      const int kbase = (kt + 1) << 7;
      #pragma unroll
      for (int s = 0; s < 5; ++s){
        int chunk = wave * 5 + s;
        const unsigned short* src = (chunk < 8)
          ? A  + (size_t)(rowA0 + chunk * 8 + stg_row) * K
          : Bt + (size_t)((chunk - 8) * 8 + stg_row) * K;
        gload_lds16((const char*)src + kbase + stg_kb, &lds[cur ^ 1][0] + chunk * 1024);
      }
    }
    const char* As = &lds[cur][0];
    const char* Bs = &lds[cur][0] + 8192;
    #pragma unroll
    for (int kk = 0; kk < 2; ++kk){
      short8 a[2], b[4];
      #pragma unroll
      for (int i = 0; i < 2; ++i){
        int row = wm * 32 + i * 16 + (lane & 15);
        int kb  = (kk * 64 + ((lane >> 4) << 4)) ^ ((row & 7) << 4);
        a[i] = *(const short8*)(As + row * 128 + kb);
      }
      #pragma unroll
      for (int j = 0; j < 4; ++j){
        int row = wn * 64 + j * 16 + (lane & 15);
        int kb  = (kk * 64 + ((lane >> 4) << 4)) ^ ((row & 7) << 4);
        b[j] = *(const short8*)(Bs + row * 128 + kb);
      }
      #pragma unroll
      for (int i = 0; i < 2; ++i)
        #pragma unroll
        for (int j = 0; j < 4; ++j)
          acc[i][j] = __builtin_amdgcn_mfma_f32_16x16x32_bf16(a[i], b[j], acc[i][j], 0, 0, 0);
    }
    __syncthreads();
    cur ^= 1;
  }

  float* red_s = (float*)&lds[0][0];     // [4][64]
  float* red_q = red_s + 256;            // [4][64]
  float* mu_a  = red_s + 512;            // [64]
  float* rs_a  = red_s + 576;            // [64]
  const int g  = lane >> 4;
  const int cl = lane & 15;
  #pragma unroll
  for (int i = 0; i < 2; ++i){
    #pragma unroll
    for (int r = 0; r < 4; ++r){
      const int rowl = wm * 32 + i * 16 + g * 4 + r;
      float s = 0.f, q = 0.f;
      #pragma unroll
      for (int j = 0; j < 4; ++j){
        float v = acc[i][j][r] +
                  bf2f(Res[(size_t)(rowA0 + rowl) * 256 + wn * 64 + j * 16 + cl]);
        acc[i][j][r] = v;
        s += v; q += v * v;
      }
      #pragma unroll
      for (int off = 1; off < 16; off <<= 1){
        s += __shfl_xor(s, off); q += __shfl_xor(q, off);
      }
      if (cl == 0){ red_s[wn * 64 + rowl] = s; red_q[wn * 64 + rowl] = q; }
    }
  }
  __syncthreads();
  if (tid < 64){
    float S = red_s[tid] + red_s[64 + tid] + red_s[128 + tid] + red_s[192 + tid];
    float Q = red_q[tid] + red_q[64 + tid] + red_q[128 + tid] + red_q[192 + tid];
    float mu = S * (1.f / 256.f);
    float var = Q * (1.f / 256.f) - mu * mu;
    mu_a[tid] = mu;
    rs_a[tid] = rsqrtf(var + 1e-5f);
  }
  __syncthreads();
  #pragma unroll
  for (int i = 0; i < 2; ++i){
    #pragma unroll
    for (int r = 0; r < 4; ++r){
      const int rowl = wm * 32 + i * 16 + g * 4 + r;
      const float mu = mu_a[rowl], rs = rs_a[rowl];
      #pragma unroll
      for (int j = 0; j < 4; ++j){
        float w = (acc[i][j][r] - mu) * rs;
        size_t idx = (size_t)(rowA0 + rowl) * 256 + wn * 64 + j * 16 + cl;
        if (OUTF32) ((float*)Out)[idx] = w;
        else        ((unsigned short*)Out)[idx] = f2bf(w);
      }
    }
  }
}

// ---------------------------------------------------------------------------
// rsa attention (round-2 verbatim): 4 tokens, 8 heads; separate Q/K/V.
// ---------------------------------------------------------------------------
__global__ __launch_bounds__(256) void attn4_kernel(
    const unsigned short* __restrict__ Q, const unsigned short* __restrict__ K,
    const unsigned short* __restrict__ V, unsigned short* __restrict__ ctx)
{
  const int t = threadIdx.x;
  const int lb = t >> 5, u = t & 31, h = u >> 2, q = u & 3;
  const size_t b = (size_t)blockIdx.x * 8 + lb;
  const size_t base = b * 1024 + h * 32;

  float qf[32];
  {
    const ushort8* qp = (const ushort8*)(Q + base + q * 256);
    #pragma unroll
    for (int g = 0; g < 4; ++g){
      ushort8 v = qp[g];
      #pragma unroll
      for (int e = 0; e < 8; ++e) qf[g * 8 + e] = bf2f(v[e]);
    }
  }
  float sc[4];
  #pragma unroll
  for (int s = 0; s < 4; ++s){
    const ushort8* kp = (const ushort8*)(K + base + s * 256);
    float a0 = 0, a1 = 0, a2 = 0, a3 = 0;
    #pragma unroll
    for (int g = 0; g < 4; ++g){
      ushort8 v = kp[g];
      a0 += qf[g*8+0]*bf2f(v[0]); a1 += qf[g*8+1]*bf2f(v[1]);
      a2 += qf[g*8+2]*bf2f(v[2]); a3 += qf[g*8+3]*bf2f(v[3]);
      a0 += qf[g*8+4]*bf2f(v[4]); a1 += qf[g*8+5]*bf2f(v[5]);
      a2 += qf[g*8+6]*bf2f(v[6]); a3 += qf[g*8+7]*bf2f(v[7]);
    }
    sc[s] = ((a0 + a1) + (a2 + a3)) * 0.17677669529663687f;
  }
  float m = fmaxf(fmaxf(sc[0], sc[1]), fmaxf(sc[2], sc[3]));
  float sum = 0.f;
  #pragma unroll
  for (int s = 0; s < 4; ++s){ sc[s] = __expf(sc[s] - m); sum += sc[s]; }
  float inv = 1.f / sum;

  float o[32];
  #pragma unroll
  for (int d = 0; d < 32; ++d) o[d] = 0.f;
  #pragma unroll
  for (int s = 0; s < 4; ++s){
    float p = sc[s] * inv;
    const ushort8* vp = (const ushort8*)(V + base + s * 256);
    #pragma unroll
    for (int g = 0; g < 4; ++g){
      ushort8 v = vp[g];
      #pragma unroll
      for (int e = 0; e < 8; ++e) o[g * 8 + e] += p * bf2f(v[e]);
    }
  }
  unsigned short* cp = ctx + base + q * 256;
  #pragma unroll
  for (int g = 0; g < 4; ++g){
    ushort8 w;
    #pragma unroll
    for (int e = 0; e < 8; ++e) w[e] = f2bf(o[g * 8 + e]);
    ((ushort8*)cp)[g] = w;
  }
}

// ---------------------------------------------------------------------------
// scatter v2 (vectorized): x2[b,c,d] = x[b,c,d] + ref[b, rid[c], d].
// ---------------------------------------------------------------------------
__global__ __launch_bounds__(256) void scatter_kernel(
    const float* __restrict__ x, const unsigned short* __restrict__ ref,
    unsigned short* __restrict__ x2)
{
  const int b = blockIdx.x, t = threadIdx.x;
  const int d0 = (t & 63) * 4;
  const int cbase = t >> 6;                    // 0..3, wave-uniform
  float rv[4][4];
  #pragma unroll
  for (int r = 0; r < 4; ++r){
    ushort4v rr = *(const ushort4v*)(ref + (size_t)b * 1024 + r * 256 + d0);
    #pragma unroll
    for (int e = 0; e < 4; ++e) rv[r][e] = bf2f(rr[e]);
  }
  const unsigned long long packed = 0x27CE40F390ull;  // rid[c] at bits [2c+1:2c]
  #pragma unroll
  for (int k = 0; k < 5; ++k){
    int c = cbase + k * 4;
    if (c < 19){
      int r = (int)((packed >> (2 * c)) & 3ull);
      floatx4 xv = *(const floatx4*)(x + (size_t)b * 4864 + c * 256 + d0);
      ushort4v w;
      #pragma unroll
      for (int e = 0; e < 4; ++e) w[e] = f2bf(xv[e] + rv[r][e]);
      *(ushort4v*)(x2 + (size_t)b * 4864 + c * 256 + d0) = w;
    }
  }
}

// ---------------------------------------------------------------------------
// lsa attention (round-2 EXACT, best measured 60.2us): 19 tokens, 8 heads.
// ---------------------------------------------------------------------------
__global__ __launch_bounds__(256) void attn19_kernel(
    const unsigned short* __restrict__ Q, const unsigned short* __restrict__ K,
    const unsigned short* __restrict__ V, unsigned short* __restrict__ ctx)
{
  __shared__ float Kl[4864];
  __shared__ float Vl[4864];
  const size_t b = blockIdx.x;
  const unsigned short* Kb = K + b * 4864;
  const unsigned short* Vb = V + b * 4864;
  for (int i = threadIdx.x; i < 4864; i += 256){ Kl[i] = bf2f(Kb[i]); Vl[i] = bf2f(Vb[i]); }
  __syncthreads();
  const int t = threadIdx.x;
  if (t >= 152) return;
  const int h = t / 19, qq = t - h * 19;

  float qf[32];
  {
    const ushort8* qp = (const ushort8*)(Q + b * 4864 + qq * 256 + h * 32);
    #pragma unroll
    for (int g = 0; g < 4; ++g){
      ushort8 v = qp[g];
      #pragma unroll
      for (int e = 0; e < 8; ++e) qf[g * 8 + e] = bf2f(v[e]);
    }
  }
  float p[19];
  float m = -1e30f;
  #pragma unroll
  for (int s = 0; s < 19; ++s){
    const float* kr = &Kl[s * 256 + h * 32];
    float a0 = 0, a1 = 0, a2 = 0, a3 = 0;
    #pragma unroll
    for (int d = 0; d < 32; d += 4){
      a0 += qf[d+0] * kr[d+0]; a1 += qf[d+1] * kr[d+1];
      a2 += qf[d+2] * kr[d+2]; a3 += qf[d+3] * kr[d+3];
    }
    p[s] = ((a0 + a1) + (a2 + a3)) * 0.17677669529663687f;
    m = fmaxf(m, p[s]);
  }
  float sum = 0.f;
  #pragma unroll
  for (int s = 0; s < 19; ++s){ p[s] = __expf(p[s] - m); sum += p[s]; }
  float inv = 1.f / sum;

  float o[32];
  #pragma unroll
  for (int d = 0; d < 32; ++d) o[d] = 0.f;
  #pragma unroll
  for (int s = 0; s < 19; ++s){
    float ps = p[s] * inv;
    const float* vr = &Vl[s * 256 + h * 32];
    #pragma unroll
    for (int d = 0; d < 32; ++d) o[d] += ps * vr[d];
  }
  unsigned short* cp = ctx + b * 4864 + qq * 256 + h * 32;
  #pragma unroll
  for (int g = 0; g < 4; ++g){
    ushort8 w;
    #pragma unroll
    for (int e = 0; e < 8; ++e) w[e] = f2bf(o[g * 8 + e]);
    ((ushort8*)cp)[g] = w;
  }
}

// ============================================================================
extern "C" void kernel_launch(void* const* d_in, const int* in_sizes, int n_in,
                              void* d_out, int out_size, void* d_ws, size_t ws_size,
                              hipStream_t stream)
{
  (void)n_in; (void)out_size;
  const float* x  = (const float*)d_in[0];
  const float* rq = (const float*)d_in[1];
  const float* rk = (const float*)d_in[2];
  const float* rv = (const float*)d_in[3];
  const float* ro = (const float*)d_in[4];
  const float* lq = (const float*)d_in[5];
  const float* lk = (const float*)d_in[6];
  const float* lv = (const float*)d_in[7];
  const float* lo = (const float*)d_in[8];
  const float* w1 = (const float*)d_in[9];
  const float* w2 = (const float*)d_in[10];

  const int B = in_sizes[0] / 4864;          // 4096
  const int M4  = B * 4;                     // 16384
  const int M19 = B * 19;                    // 77824
  const int MH  = M19 / 2;                   // 38912
  const size_t MB = 1ull << 20;
  if (ws_size < 240 * MB) return;

  char* ws = (char*)d_ws;
  unsigned short* WT    = (unsigned short*)(ws);
  unsigned short* FE    = (unsigned short*)(ws + 2   * MB);
  unsigned short* Q4    = (unsigned short*)(ws + 10  * MB);
  unsigned short* K4    = (unsigned short*)(ws + 18  * MB);
  unsigned short* V4    = (unsigned short*)(ws + 26  * MB);
  unsigned short* CTX4  = (unsigned short*)(ws + 34  * MB);
  unsigned short* REF   = (unsigned short*)(ws + 42  * MB);
  unsigned short* X2    = (unsigned short*)(ws + 50  * MB);
  unsigned short* Q19   = (unsigned short*)(ws + 88  * MB);
  unsigned short* K19   = (unsigned short*)(ws + 126 * MB);
  unsigned short* V19   = (unsigned short*)(ws + 164 * MB);
  unsigned short* CTX19 = (unsigned short*)(ws + 202 * MB);
  unsigned short* FUSED = (unsigned short*)(ws + 88  * MB);  // alias Q19 (dead)
  unsigned short* H     = (unsigned short*)(ws + 126 * MB);  // alias K19+V19 (dead)
  float* out = (float*)d_out;

  // 1. weights -> bf16 [n][k]
  wprep_all<<<4096, 256, 0, stream>>>(rq, rk, rv, ro, lq, lk, lv, lo, w1, w2, WT);
  // 2. region pool
  pool_kernel<<<B, 256, 0, stream>>>(x, FE);
  // 3. rsa QKV (one pass, split epilogue; 6*128 grid, %8==0)
  gemm_kernel<0,1,6><<<6 * (M4/128), 256, 0, stream>>>(FE, WT, Q4, K4, V4, M4, 768, 256);
  // 4. rsa attention
  attn4_kernel<<<B/8, 256, 0, stream>>>(Q4, K4, V4, CTX4);
  // 5. rsa out-proj + LN(.. + fe) -> REF
  gemm_ln_kernel<0><<<M4/64, 512, 0, stream>>>(CTX4, WT + 3*65536, FE, REF, M4, 256);
  // 6. x2 = x + ref[rid]
  scatter_kernel<<<B, 256, 0, stream>>>(x, REF, X2);
  // 7. lsa QKV (one pass, split epilogue; 6*608 grid, %8==0)
  gemm_kernel<0,1,6><<<6 * (M19/128), 256, 0, stream>>>(X2, WT + 4*65536, Q19, K19, V19, M19, 768, 256);
  // 8. lsa attention
  attn19_kernel<<<B, 256, 0, stream>>>(Q19, K19, V19, CTX19);
  // 9. lsa out-proj + LN(.. + x2) -> FUSED   (Q19 dead)
  gemm_ln_kernel<0><<<M19/64, 512, 0, stream>>>(CTX19, WT + 7*65536, X2, FUSED, M19, 256);
  // 10. FFN halves: H = relu(FUSED @ w1); out = LN(H @ w2 + FUSED)
  for (int hf = 0; hf < 2; ++hf){
    const unsigned short* Fh = FUSED + (size_t)hf * MH * 256;
    gemm_kernel<1,0,8><<<8 * (MH/128), 256, 0, stream>>>(Fh, WT + 524288, H, nullptr, nullptr, MH, 1024, 256);
    gemm_ln_kernel<1><<<MH/64, 512, 0, stream>>>(H, WT + 786432, Fh,
                                                 out + (size_t)hf * MH * 256, MH, 1024);
  }
}